// Round 1
// 3953.752 us; speedup vs baseline: 1.2711x; 1.2711x over previous
//
#include <hip/hip_runtime.h>
#include <hip/hip_bf16.h>

// Persistent fused kernel, v2: 256 blocks x 1024 threads (16 waves, 4/SIMD).
// Each block owns 16 batch rows and runs encoder + all 63 decoder steps
// locally. v1 used 128 blocks x 512 thr with 114KB LDS -> only 128/256 CUs
// and 2 waves/SIMD; counters showed Occupancy 11.4%, MfmaUtil 4.4%, and
// ~23MB/step HBM re-fetch of the 2MB weight set (L2 thrashed by out writes).
// v2: fill all CUs, 2x waves/SIMD, nontemporal out stores to keep weights
// L2-resident, enc_h + gh + biases held in registers (gh shrinks 96->24 regs
// so weight loads can actually pipeline under the 128-VGPR cap).
//
// DTYPE-AGNOSTIC: probe classifies bn_var bit pattern; bf16-native and fp32
// variants both launch, each no-ops unless the flag matches. fp32 mode
// pre-converts weights to bf16 in d_ws when it fits.

typedef unsigned short u16;
typedef __attribute__((ext_vector_type(8))) short short8;
typedef __attribute__((ext_vector_type(4))) float f32x4;
typedef __bf16 bf16x8 __attribute__((ext_vector_type(8)));

#define TDIM 64
#define HDIM 512
#define ODIM 256
#define RROWS 16
#define NBLK 256
#define NTHR 1024     // 16 waves -> 4 waves/SIMD, 1 block/CU
#define PITCH 520     // 512+8: breaks ds_read_b128 bank aliasing
#define PITCH_O 264   // 256+8

// ws layout (u16 elems, after 64-byte flag header)
#define WS_LINW   0u
#define WS_DECWIH 131072u
#define WS_OUTW   917504u
#define WS_PREWIH 1048576u
#define WS_DECWHH 1835008u
#define WS_TOTAL  2621440u

__device__ inline float b2f(u16 u) {
    unsigned v = ((unsigned)u) << 16;
    float f; __builtin_memcpy(&f, &v, 4); return f;
}
__device__ inline u16 f2b(float f) {   // RNE
    unsigned u; __builtin_memcpy(&u, &f, 4);
    return (u16)((u + 0x7fffu + ((u >> 16) & 1u)) >> 16);
}
__device__ inline float sigm(float x) {
    return __builtin_amdgcn_rcpf(1.f + __expf(-x));
}
__device__ inline float tanh_f(float x) {
    return 1.f - 2.f * __builtin_amdgcn_rcpf(1.f + __expf(2.f * x));
}
__device__ inline f32x4 mfma16(short8 a, short8 b, f32x4 c) {
    return __builtin_amdgcn_mfma_f32_16x16x32_bf16(
        __builtin_bit_cast(bf16x8, a), __builtin_bit_cast(bf16x8, b), c, 0, 0, 0);
}

template<int WF32> __device__ inline short8 ldw8(const void* p, size_t off) {
    if constexpr (!WF32) {
        return *(const short8*)((const u16*)p + off);
    } else {
        const float* f = (const float*)p + off;
        f32x4 a = *(const f32x4*)f, b = *(const f32x4*)(f + 4);
        short8 r;
        r[0] = (short)f2b(a[0]); r[1] = (short)f2b(a[1]);
        r[2] = (short)f2b(a[2]); r[3] = (short)f2b(a[3]);
        r[4] = (short)f2b(b[0]); r[5] = (short)f2b(b[1]);
        r[6] = (short)f2b(b[2]); r[7] = (short)f2b(b[3]);
        return r;
    }
}
template<int IOF32> __device__ inline float ldf(const void* p, int i) {
    if constexpr (IOF32) return ((const float*)p)[i];
    else return b2f(((const u16*)p)[i]);
}

// ---- probe: bn_var in [0.5,1.5]. bf16 buffer -> all u16s match the
// 0x3F00/0x3F80 pattern; fp32 buffer -> only the 8 high-halves do. ----
__global__ void probe_k(const u16* __restrict__ bnv, int* __restrict__ flag) {
    if (threadIdx.x == 0 && blockIdx.x == 0) {
        int hits = 0;
        for (int i = 0; i < 16; ++i) {
            u16 m = (u16)(bnv[i] & 0xFF80u);
            hits += (m == 0x3F00u || m == 0x3F80u) ? 1 : 0;
        }
        *flag = (hits >= 14) ? 1 : 0;   // 1 = bf16 inputs, 0 = fp32 inputs
    }
}

// ---- fp32 mode: round weights to bf16 into ws (runs only when flag==0) ----
__global__ void cvtw_k(const int* __restrict__ flag,
                       const float* __restrict__ linW,
                       const float* __restrict__ decWih,
                       const float* __restrict__ outW,
                       const float* __restrict__ preWih,
                       const float* __restrict__ decWhh,
                       u16* __restrict__ dst) {
    if (*flag == 1) return;
    int i = blockIdx.x * blockDim.x + threadIdx.x;
    const int st = gridDim.x * blockDim.x;
    for (; i < (int)WS_TOTAL; i += st) {
        int j = i; const float* s;
        if (j < 131072) s = linW + j;
        else if ((j -= 131072) < 786432) s = decWih + j;
        else if ((j -= 786432) < 131072) s = outW + j;
        else if ((j -= 131072) < 786432) s = preWih + j;
        else { j -= 786432; s = decWhh + j; }
        dst[i] = f2b(*s);
    }
}

// WF32: weight pointers are fp32 (convert per-fragment). IOF32: biases/emb
// read as fp32 and output written as fp32. Runs only when flag matches.
template<int WF32, int IOF32>
__global__ __launch_bounds__(NTHR, 4)
void c2g_kernel(const int* __restrict__ flag,
                const int* __restrict__ cluster,
                const void* __restrict__ emb,
                const void* __restrict__ preWih,
                const void* __restrict__ preBih,
                const void* __restrict__ preBhh,
                const void* __restrict__ linW,
                const void* __restrict__ linB,
                const void* __restrict__ bnG,
                const void* __restrict__ bnB,
                const void* __restrict__ bnM,
                const void* __restrict__ bnV,
                const void* __restrict__ decWih,
                const void* __restrict__ decBih,
                const void* __restrict__ decWhh,
                const void* __restrict__ decBhh,
                const void* __restrict__ outW,
                const void* __restrict__ outB,
                void* __restrict__ out)
{
    if ((*flag == 1) == (IOF32 != 0)) return;   // proceed only on dtype match

    __shared__ __align__(16) u16 x_lds[RROWS * PITCH];
    __shared__ __align__(16) u16 h_lds[RROWS * PITCH];
    __shared__ __align__(16) u16 e_lds[RROWS * PITCH];
    __shared__ __align__(16) u16 o_lds[RROWS * PITCH_O];
    // 3*16640 + 8448 = 58368 B -> 1 block/CU, 16 waves resident

    const int tid  = threadIdx.x;
    const int wave = tid >> 6;    // 0..15
    const int lane = tid & 63;
    const int n16  = lane & 15;   // MFMA col (feature j within 16-tile) / A-row
    const int q    = lane >> 4;   // K-quad for A/B frags; row-quad for C
    const int blk  = blockIdx.x;
    const int r0   = blk * RROWS;

    // ---- init: zero decoder input, zero output frame 0, gather embeddings --
    for (int i = tid; i < RROWS * PITCH_O; i += NTHR) o_lds[i] = 0;
    for (int i = tid; i < RROWS * ODIM; i += NTHR) {
        int m = i >> 8, c = i & 255;
        size_t idx = (size_t)(r0 + m) * TDIM * ODIM + c;
        if constexpr (IOF32) __builtin_nontemporal_store(0.f, (float*)out + idx);
        else                 __builtin_nontemporal_store((u16)0, (u16*)out + idx);
    }
    for (int i = tid; i < RROWS * HDIM; i += NTHR) {
        int m = i >> 9, c = i & 511;
        x_lds[m * PITCH + c] =
            f2b(ldf<IOF32>(emb, cluster[r0 + m] * HDIM + c));
    }
    __syncthreads();

    const int jc0 = (wave * 2 + 0) * 16 + n16;
    const int jc1 = (wave * 2 + 1) * 16 + n16;
    const int jc3 = wave * 16 + n16;            // G3 column (0..255)

    // ---- encoder GRU (h0 = 0 -> hh-gates are just pre_b_hh) ----
    // enc_h kept BOTH in registers (same thread consumes it in G2 every step)
    // and in e_lds (A-operand for the gh matmul below).
    f32x4 ehr[2];
    #pragma unroll
    for (int i = 0; i < 2; ++i) {
        const int jc = i ? jc1 : jc0;
        f32x4 ar = {0,0,0,0}, az = {0,0,0,0}, an = {0,0,0,0};
        #pragma unroll 4
        for (int kc = 0; kc < 16; ++kc) {
            const int ko = kc * 32 + q * 8;
            short8 a0 = *(const short8*)&x_lds[n16 * PITCH + ko];
            short8 br = ldw8<WF32>(preWih, (size_t)(jc)        * HDIM + ko);
            short8 bz = ldw8<WF32>(preWih, (size_t)(512 + jc)  * HDIM + ko);
            short8 bn = ldw8<WF32>(preWih, (size_t)(1024 + jc) * HDIM + ko);
            ar = mfma16(a0, br, ar); az = mfma16(a0, bz, az); an = mfma16(a0, bn, an);
        }
        const float bir = ldf<IOF32>(preBih, jc);
        const float biz = ldf<IOF32>(preBih, 512 + jc);
        const float bin = ldf<IOF32>(preBih, 1024 + jc);
        const float ghr = ldf<IOF32>(preBhh, jc);
        const float ghz = ldf<IOF32>(preBhh, 512 + jc);
        const float ghn = ldf<IOF32>(preBhh, 1024 + jc);
        #pragma unroll
        for (int r = 0; r < 4; ++r) {
            float rr = sigm(ar[r] + bir + ghr);
            float zz = sigm(az[r] + biz + ghz);
            float nn = tanh_f(an[r] + bin + rr * ghn);
            float ev = (1.f - zz) * nn;
            ehr[i][r] = ev;
            e_lds[(q * 4 + r) * PITCH + jc] = f2b(ev);
        }
    }
    __syncthreads();

    // ---- gh = enc_h @ dec_W_hh^T + dec_b_hh (+ dec_b_ih folded for r,z) ----
    f32x4 gh[2][3];
    #pragma unroll
    for (int i = 0; i < 2; ++i) {
        const int jc = i ? jc1 : jc0;
        f32x4 ar = {0,0,0,0}, az = {0,0,0,0}, an = {0,0,0,0};
        #pragma unroll 4
        for (int kc = 0; kc < 16; ++kc) {
            const int ko = kc * 32 + q * 8;
            short8 a0 = *(const short8*)&e_lds[n16 * PITCH + ko];
            short8 br = ldw8<WF32>(decWhh, (size_t)(jc)        * HDIM + ko);
            short8 bz = ldw8<WF32>(decWhh, (size_t)(512 + jc)  * HDIM + ko);
            short8 bn = ldw8<WF32>(decWhh, (size_t)(1024 + jc) * HDIM + ko);
            ar = mfma16(a0, br, ar); az = mfma16(a0, bz, az); an = mfma16(a0, bn, an);
        }
        const float cr = ldf<IOF32>(decBhh, jc)        + ldf<IOF32>(decBih, jc);
        const float cz = ldf<IOF32>(decBhh, 512 + jc)  + ldf<IOF32>(decBih, 512 + jc);
        const float cn = ldf<IOF32>(decBhh, 1024 + jc);
        #pragma unroll
        for (int r = 0; r < 4; ++r) {
            gh[i][0][r] = ar[r] + cr;
            gh[i][1][r] = az[r] + cz;
            gh[i][2][r] = an[r] + cn;
        }
    }

    // ---- hoisted loop-invariant scalars ----
    float c_s[2], c_o[2], c_bin[2];
    #pragma unroll
    for (int i = 0; i < 2; ++i) {
        const int jc = i ? jc1 : jc0;
        const float s = ldf<IOF32>(bnG, jc) *
            __builtin_amdgcn_rcpf(sqrtf(ldf<IOF32>(bnV, jc) + 1e-5f));
        c_s[i] = s;
        c_o[i] = (ldf<IOF32>(linB, jc) - ldf<IOF32>(bnM, jc)) * s
               + ldf<IOF32>(bnB, jc);
        c_bin[i] = ldf<IOF32>(decBih, 1024 + jc);
    }
    const float c_ob = ldf<IOF32>(outB, jc3);
    // no barrier needed: G1 writes x_lds (last read pre-barrier), reads o_lds
    // (stable); other waves still in gh read only e_lds.

    // ---- 63 decoder steps; activations stay in LDS/registers ----
    for (int t = 0; t < TDIM - 1; ++t) {
        // G1: x = relu(bn(o @ lin_W^T + lin_b)), K=256
        #pragma unroll
        for (int i = 0; i < 2; ++i) {
            const int jc = i ? jc1 : jc0;
            f32x4 a = {0,0,0,0};
            #pragma unroll
            for (int kc = 0; kc < 8; ++kc) {
                const int ko = kc * 32 + q * 8;
                short8 bw = ldw8<WF32>(linW, (size_t)jc * ODIM + ko);
                short8 f0 = *(const short8*)&o_lds[n16 * PITCH_O + ko];
                a = mfma16(f0, bw, a);
            }
            #pragma unroll
            for (int r = 0; r < 4; ++r) {
                float xv = a[r] * c_s[i] + c_o[i];
                x_lds[(q * 4 + r) * PITCH + jc] = f2b(fmaxf(xv, 0.f));
            }
        }
        __syncthreads();

        // G2: gi = x @ dec_W_ih^T; gates fused with register gh / ehr
        #pragma unroll
        for (int i = 0; i < 2; ++i) {
            const int jc = i ? jc1 : jc0;
            f32x4 ar = {0,0,0,0}, az = {0,0,0,0}, an = {0,0,0,0};
            #pragma unroll 4
            for (int kc = 0; kc < 16; ++kc) {
                const int ko = kc * 32 + q * 8;
                short8 a0 = *(const short8*)&x_lds[n16 * PITCH + ko];
                short8 br = ldw8<WF32>(decWih, (size_t)(jc)        * HDIM + ko);
                short8 bz = ldw8<WF32>(decWih, (size_t)(512 + jc)  * HDIM + ko);
                short8 bn = ldw8<WF32>(decWih, (size_t)(1024 + jc) * HDIM + ko);
                ar = mfma16(a0, br, ar); az = mfma16(a0, bz, az); an = mfma16(a0, bn, an);
            }
            #pragma unroll
            for (int r = 0; r < 4; ++r) {
                float rr = sigm(ar[r] + gh[i][0][r]);
                float zz = sigm(az[r] + gh[i][1][r]);
                float nn = tanh_f(an[r] + c_bin[i] + rr * gh[i][2][r]);
                h_lds[(q * 4 + r) * PITCH + jc] =
                    f2b((1.f - zz) * nn + zz * ehr[i][r]);
            }
        }
        __syncthreads();

        // G3: out = h @ out_W^T + out_b, K=512, N=256; write global + o_lds
        {
            f32x4 a = {0,0,0,0};
            #pragma unroll 4
            for (int kc = 0; kc < 16; ++kc) {
                const int ko = kc * 32 + q * 8;
                short8 bw = ldw8<WF32>(outW, (size_t)jc3 * HDIM + ko);
                short8 f0 = *(const short8*)&h_lds[n16 * PITCH + ko];
                a = mfma16(f0, bw, a);
            }
            #pragma unroll
            for (int r = 0; r < 4; ++r) {
                float val = a[r] + c_ob;
                int row = q * 4 + r;
                o_lds[row * PITCH_O + jc3] = f2b(val);
                size_t idx = (size_t)(r0 + row) * TDIM * ODIM
                           + (size_t)(t + 1) * ODIM + jc3;
                if constexpr (IOF32)
                    __builtin_nontemporal_store(val, (float*)out + idx);
                else
                    __builtin_nontemporal_store(f2b(val), (u16*)out + idx);
            }
        }
        __syncthreads();
    }
}

extern "C" void kernel_launch(void* const* d_in, const int* in_sizes, int n_in,
                              void* d_out, int out_size, void* d_ws, size_t ws_size,
                              hipStream_t stream) {
    const int* cluster = (const int*)d_in[0];
    // d_in[1] = out_poses: only shape matters (T frames), values unused
    // d_in[4] = pre_W_hh: dead (h0 == 0)
    int* flag = (int*)d_ws;
    u16* wsW  = (u16*)((char*)d_ws + 64);
    const size_t NEED = 64 + (size_t)WS_TOTAL * 2;

    probe_k<<<dim3(1), dim3(64), 0, stream>>>((const u16*)d_in[12], flag);

    // bf16-native variant (no-ops unless flag==1)
    c2g_kernel<0, 0><<<dim3(NBLK), dim3(NTHR), 0, stream>>>(
        flag, cluster, d_in[2], d_in[3], d_in[5], d_in[6], d_in[7], d_in[8],
        d_in[9], d_in[10], d_in[11], d_in[12], d_in[13], d_in[15], d_in[14],
        d_in[16], d_in[17], d_in[18], d_out);

    if (ws_size >= NEED) {
        // fp32 mode with pre-converted bf16 weights in ws
        cvtw_k<<<dim3(2048), dim3(256), 0, stream>>>(
            flag, (const float*)d_in[7], (const float*)d_in[13],
            (const float*)d_in[17], (const float*)d_in[3],
            (const float*)d_in[14], wsW);
        c2g_kernel<0, 1><<<dim3(NBLK), dim3(NTHR), 0, stream>>>(
            flag, cluster, d_in[2], wsW + WS_PREWIH, d_in[5], d_in[6],
            wsW + WS_LINW, d_in[8], d_in[9], d_in[10], d_in[11], d_in[12],
            wsW + WS_DECWIH, d_in[15], wsW + WS_DECWHH, d_in[16],
            wsW + WS_OUTW, d_in[18], d_out);
    } else {
        // fp32 mode, convert weights per-fragment on the fly
        c2g_kernel<1, 1><<<dim3(NBLK), dim3(NTHR), 0, stream>>>(
            flag, cluster, d_in[2], d_in[3], d_in[5], d_in[6], d_in[7], d_in[8],
            d_in[9], d_in[10], d_in[11], d_in[12], d_in[13], d_in[15], d_in[14],
            d_in[16], d_in[17], d_in[18], d_out);
    }
}